// Round 1
// baseline (741.509 us; speedup 1.0000x reference)
//
#include <hip/hip_runtime.h>

// QuatE scoring, MI355X. fp32 emulated via bf16 hi/lo split (3 MFMA products),
// fused GEMM C[4096x1024] = [h;t] @ [W_er;W_ei;W_ej;W_ek]^T, r-GEMM, fused epilogue.

using bf16x8 = __attribute__((ext_vector_type(8))) short;
using f32x16 = __attribute__((ext_vector_type(16))) float;

#define DEVINL static __device__ __forceinline__

// barrier WITHOUT vmcnt drain (global reg-loads stay in flight across it)
DEVINL void bar_sync() {
  asm volatile("s_waitcnt lgkmcnt(0)" ::: "memory");
  __builtin_amdgcn_s_barrier();
  asm volatile("" ::: "memory");
}

// split two fp32 into packed bf16 hi pair + lo pair (bit-truncation split;
// x = hi + lo + eps, |eps| <= 2^-16 |x|)
DEVINL void split2(float x0, float x1, unsigned& h, unsigned& l) {
  unsigned u0 = __float_as_uint(x0), u1 = __float_as_uint(x1);
  unsigned h0 = u0 & 0xFFFF0000u, h1 = u1 & 0xFFFF0000u;
  h = (u0 >> 16) | h1;
  float r0 = x0 - __uint_as_float(h0);
  float r1 = x1 - __uint_as_float(h1);
  l = (__float_as_uint(r0) >> 16) | (__float_as_uint(r1) & 0xFFFF0000u);
}

// ---------------- weight conversion: fp32 [rows][srcCols] -> bf16 hi/lo [rows][dstCols] (zero-pad tail)
__global__ void convert_w(const float* __restrict__ src, int srcCols,
                          unsigned short* __restrict__ dhi, unsigned short* __restrict__ dlo,
                          int dstCols)
{
  int row = blockIdx.y;
  int c4 = blockIdx.x * blockDim.x + threadIdx.x;
  if (c4 * 4 >= dstCols) return;
  int k = c4 * 4;
  float x0 = 0.f, x1 = 0.f, x2 = 0.f, x3 = 0.f;
  const float* s = src + (size_t)row * srcCols + k;
  if (k + 3 < srcCols) {
    float4 v = *(const float4*)s;
    x0 = v.x; x1 = v.y; x2 = v.z; x3 = v.w;
  } else {
    if (k + 0 < srcCols) x0 = s[0];
    if (k + 1 < srcCols) x1 = s[1];
    if (k + 2 < srcCols) x2 = s[2];
    if (k + 3 < srcCols) x3 = s[3];
  }
  unsigned h0, l0, h1, l1;
  split2(x0, x1, h0, l0);
  split2(x2, x3, h1, l1);
  *(uint2*)(dhi + (size_t)row * dstCols + k) = make_uint2(h0, h1);
  *(uint2*)(dlo + (size_t)row * dstCols + k) = make_uint2(l0, l1);
}

// ---------------- r padding: fp32 [2048][500] -> fp32 [2048][512] zero-padded
__global__ void pad_r(const float* __restrict__ src, float* __restrict__ dst)
{
  int row = blockIdx.y;
  int c4 = threadIdx.x;          // 0..127
  int k = c4 * 4;
  float4 v = make_float4(0.f, 0.f, 0.f, 0.f);
  if (k + 3 < 500) v = *(const float4*)(src + (size_t)row * 500 + k);
  *(float4*)(dst + (size_t)row * 512 + k) = v;
}

// ---------------- fused split GEMM ----------------
// C[ks][M][N] (+)= A_hi * B_hi + A_lo * B_hi + A_hi * B_lo   (per k-split buffer)
// A fp32 row-major (converted on the fly), B = W bf16 hi/lo, layout [N][K] (= B^T).
// Tile 128x128, BK=32, 256 threads (4 waves, 2x2), 32x32x16 bf16 MFMA.
struct StageRegs {
  float4 a[4];
  uint4 bh[2], bl[2];
};

__global__ __launch_bounds__(256, 2) void gemm_split(
    const float* __restrict__ A0, const float* __restrict__ A1, int mtA0, long lda,
    const unsigned short* __restrict__ Bhi, const unsigned short* __restrict__ Blo, long ldb,
    float* __restrict__ C, long ldc,
    int MT, int NT, int KS, int Ksteps)
{
  __shared__ __align__(16) char lds[32768];
  char* sAhi = lds;
  char* sAlo = lds + 8192;
  char* sBhi = lds + 16384;
  char* sBlo = lds + 24576;

  const int tid = threadIdx.x;
  const int bid = blockIdx.x;
  const int per = MT * NT;
  const int ks  = bid / per;
  const int rr  = bid - ks * per;
  const int nt  = rr % NT;
  const int mt  = rr / NT;

  const int s0  = (Ksteps * ks) / KS;
  const int s1  = (Ksteps * (ks + 1)) / KS;
  const int nst = s1 - s0;
  const long kbase = (long)s0 * 32;

  const float* Ablk = (mt < mtA0) ? (A0 + (size_t)mt * 128 * lda)
                                  : (A1 + (size_t)(mt - mtA0) * 128 * lda);
  const long tileN = (long)nt * 128;
  float* Cb = C + (size_t)ks * (size_t)(MT * 128) * (size_t)ldc;

  const int lane = tid & 63;
  const int wid  = tid >> 6;
  const int wr   = wid >> 1, wc = wid & 1;
  const int rl   = lane & 31;
  const int kg   = lane >> 5;

  // per-lane LDS fragment byte offsets (constant over K loop).
  // element (row,k) lives at byte: row*64 + ((k>>3) ^ ((row>>1)&3))*16 + (k&7)*2
  int aoff[2][2], boff[2][2];
#pragma unroll
  for (int m = 0; m < 2; ++m)
#pragma unroll
    for (int kk = 0; kk < 2; ++kk) {
      int arow = wr * 64 + m * 32 + rl;
      aoff[m][kk] = arow * 64 + ((((kk << 1) + kg) ^ ((arow >> 1) & 3)) << 4);
      int brow = wc * 64 + m * 32 + rl;
      boff[m][kk] = brow * 64 + ((((kk << 1) + kg) ^ ((brow >> 1) & 3)) << 4);
    }

  f32x16 acc[2][2];
#pragma unroll
  for (int m = 0; m < 2; ++m)
#pragma unroll
    for (int n = 0; n < 2; ++n)
#pragma unroll
      for (int i = 0; i < 16; ++i) acc[m][n][i] = 0.f;

  StageRegs R0, R1;

  auto stage_load = [&](StageRegs& Rg, long kt) {
#pragma unroll
    for (int it = 0; it < 4; ++it) {          // A: 128 rows x 32 f32
      int g = it * 256 + tid;
      int row = g >> 3, col4 = g & 7;
      Rg.a[it] = *(const float4*)(Ablk + (size_t)row * lda + kt + col4 * 4);
    }
#pragma unroll
    for (int it = 0; it < 2; ++it) {          // B: 128 rows x 32 bf16 (hi & lo)
      int s = it * 256 + tid;
      long row = tileN + (s >> 2);
      int c = s & 3;
      Rg.bh[it] = *(const uint4*)(Bhi + (size_t)row * ldb + kt + c * 8);
      Rg.bl[it] = *(const uint4*)(Blo + (size_t)row * ldb + kt + c * 8);
    }
  };

  auto stage_write = [&](StageRegs& Rg) {
#pragma unroll
    for (int it = 0; it < 4; ++it) {
      int g = it * 256 + tid;
      int row = g >> 3, col4 = g & 7;
      unsigned h0, l0, h1, l1;
      split2(Rg.a[it].x, Rg.a[it].y, h0, l0);
      split2(Rg.a[it].z, Rg.a[it].w, h1, l1);
      int off = row * 64 + ((((col4 >> 1) ^ ((row >> 1) & 3)) << 4) + ((col4 & 1) << 3));
      *(uint2*)(sAhi + off) = make_uint2(h0, h1);
      *(uint2*)(sAlo + off) = make_uint2(l0, l1);
    }
#pragma unroll
    for (int it = 0; it < 2; ++it) {
      int s = it * 256 + tid;
      int row = s >> 2, c = s & 3;
      int off = row * 64 + ((c ^ ((row >> 1) & 3)) << 4);
      *(uint4*)(sBhi + off) = Rg.bh[it];
      *(uint4*)(sBlo + off) = Rg.bl[it];
    }
  };

  auto compute = [&]() {
    bf16x8 ah[2][2], al[2][2];
#pragma unroll
    for (int m = 0; m < 2; ++m)
#pragma unroll
      for (int kk = 0; kk < 2; ++kk) {
        ah[m][kk] = *(const bf16x8*)(sAhi + aoff[m][kk]);
        al[m][kk] = *(const bf16x8*)(sAlo + aoff[m][kk]);
      }
#pragma unroll
    for (int n = 0; n < 2; ++n) {
      bf16x8 bh0 = *(const bf16x8*)(sBhi + boff[n][0]);
      bf16x8 bh1 = *(const bf16x8*)(sBhi + boff[n][1]);
      bf16x8 bl0 = *(const bf16x8*)(sBlo + boff[n][0]);
      bf16x8 bl1 = *(const bf16x8*)(sBlo + boff[n][1]);
#pragma unroll
      for (int m = 0; m < 2; ++m) {
        acc[m][n] = __builtin_amdgcn_mfma_f32_32x32x16_bf16(ah[m][0], bh0, acc[m][n], 0, 0, 0);
        acc[m][n] = __builtin_amdgcn_mfma_f32_32x32x16_bf16(ah[m][1], bh1, acc[m][n], 0, 0, 0);
        acc[m][n] = __builtin_amdgcn_mfma_f32_32x32x16_bf16(al[m][0], bh0, acc[m][n], 0, 0, 0);
        acc[m][n] = __builtin_amdgcn_mfma_f32_32x32x16_bf16(al[m][1], bh1, acc[m][n], 0, 0, 0);
        acc[m][n] = __builtin_amdgcn_mfma_f32_32x32x16_bf16(ah[m][0], bl0, acc[m][n], 0, 0, 0);
        acc[m][n] = __builtin_amdgcn_mfma_f32_32x32x16_bf16(ah[m][1], bl1, acc[m][n], 0, 0, 0);
      }
    }
  };

  stage_load(R0, kbase);
  for (int t = 0; t < nst; ++t) {
    if (t & 1) {
      stage_write(R1);
      if (t + 1 < nst) stage_load(R0, kbase + (long)(t + 1) * 32);
    } else {
      stage_write(R0);
      if (t + 1 < nst) stage_load(R1, kbase + (long)(t + 1) * 32);
    }
    bar_sync();   // ds writes visible; global loads stay in flight
    compute();
    bar_sync();   // all waves done reading before next overwrite
  }

  // C write. 32x32 D layout: col = lane&31, row = (reg&3) + 8*(reg>>2) + 4*(lane>>5)
  const long tileM = (long)mt * 128;
#pragma unroll
  for (int m = 0; m < 2; ++m)
#pragma unroll
    for (int n = 0; n < 2; ++n)
#pragma unroll
      for (int reg = 0; reg < 16; ++reg) {
        long crow = tileM + wr * 64 + m * 32 + (reg & 3) + 8 * (reg >> 2) + 4 * kg;
        long ccol = tileN + wc * 64 + n * 32 + rl;
        Cb[(size_t)crow * ldc + ccol] = acc[m][n][reg];
      }
}

// ---------------- epilogue: k-split sum, norm, Hamilton, row dot, sigmoid ----------------
__global__ void epilogue_kernel(const float* __restrict__ C1, const float* __restrict__ C2,
                                float* __restrict__ out)
{
  const int b = blockIdx.x;        // 0..2047
  const int d = threadIdx.x;       // 0..255
  const size_t SZ = 4096ull * 1024ull;   // k-split stride of C1
  const float* h0 = C1 + (size_t)b * 1024;
  const float* t0 = C1 + (size_t)(b + 2048) * 1024;
  const float* rp = C2 + (size_t)b * 1024;

  float Hq[4], Tq[4], Rq[4];
#pragma unroll
  for (int q = 0; q < 4; ++q) {
    Hq[q] = h0[q * 256 + d] + h0[SZ + q * 256 + d];
    Tq[q] = t0[q * 256 + d] + t0[SZ + q * 256 + d];
    Rq[q] = rp[q * 256 + d];
  }
  float nn = Rq[0]*Rq[0] + Rq[1]*Rq[1] + Rq[2]*Rq[2] + Rq[3]*Rq[3];
  float Qr = Hq[0]*Rq[0] - Hq[1]*Rq[1] - Hq[2]*Rq[2] - Hq[3]*Rq[3];
  float Qi = Hq[0]*Rq[1] + Hq[1]*Rq[0] + Hq[2]*Rq[3] - Hq[3]*Rq[2];
  float Qj = Hq[0]*Rq[2] - Hq[1]*Rq[3] + Hq[2]*Rq[0] + Hq[3]*Rq[1];
  float Qk = Hq[0]*Rq[3] + Hq[1]*Rq[2] - Hq[2]*Rq[1] + Hq[3]*Rq[0];
  float ss = Qr*Tq[0] + Qi*Tq[1] + Qj*Tq[2] + Qk*Tq[3];

#pragma unroll
  for (int o = 32; o; o >>= 1) {
    ss += __shfl_xor(ss, o);
    nn += __shfl_xor(nn, o);
  }
  __shared__ float red[8];
  int lane = d & 63, w = d >> 6;
  if (lane == 0) { red[w] = ss; red[4 + w] = nn; }
  __syncthreads();
  if (d == 0) {
    float S = red[0] + red[1] + red[2] + red[3];
    float N = red[4] + red[5] + red[6] + red[7];
    float score = sqrtf(N) * S;       // score is linear in R -> scale once by norm
    out[b] = 1.f / (1.f + expf(-score));
  }
}

// ---------------- launch ----------------
extern "C" void kernel_launch(void* const* d_in, const int* in_sizes, int n_in,
                              void* d_out, int out_size, void* d_ws, size_t ws_size,
                              hipStream_t stream)
{
  const float* h = (const float*)d_in[0];
  const float* t = (const float*)d_in[1];
  const float* r = (const float*)d_in[2];
  const float* We[4] = {(const float*)d_in[3], (const float*)d_in[4],
                        (const float*)d_in[5], (const float*)d_in[6]};
  const float* Wr[4] = {(const float*)d_in[7], (const float*)d_in[8],
                        (const float*)d_in[9], (const float*)d_in[10]};
  float* out = (float*)d_out;

  char* ws = (char*)d_ws;
  unsigned short* Whi  = (unsigned short*)(ws + 0);            // [1024][20000] bf16
  unsigned short* Wlo  = (unsigned short*)(ws + 40960000);     // [1024][20000]
  unsigned short* Wrhi = (unsigned short*)(ws + 81920000);     // [1024][512]
  unsigned short* Wrlo = (unsigned short*)(ws + 82968576);     // [1024][512]
  float*          rpad = (float*)(ws + 84017152);              // [2048][512] f32
  float*          C1   = (float*)(ws + 88211456);              // [2][4096][1024] f32
  float*          C2   = (float*)(ws + 121765888);             // [2048][1024] f32
  // total = 130,154,496 bytes

  for (int q = 0; q < 4; ++q) {
    convert_w<<<dim3(20, 256), 256, 0, stream>>>(
        We[q], 20000, Whi + (size_t)q * 256 * 20000, Wlo + (size_t)q * 256 * 20000, 20000);
    convert_w<<<dim3(1, 256), 256, 0, stream>>>(
        Wr[q], 500, Wrhi + (size_t)q * 256 * 512, Wrlo + (size_t)q * 256 * 512, 512);
  }
  pad_r<<<dim3(1, 2048), 128, 0, stream>>>(r, rpad);

  // main: M=4096 (h;t), N=1024, K=20000; MT=32 NT=8 KS=2, 625 K-steps
  gemm_split<<<dim3(32 * 8 * 2), 256, 0, stream>>>(
      h, t, 16, 20000L, Whi, Wlo, 20000L, C1, 1024L, 32, 8, 2, 625);
  // r: M=2048, N=1024, K=512; MT=16 NT=8 KS=1, 16 K-steps
  gemm_split<<<dim3(16 * 8), 256, 0, stream>>>(
      rpad, rpad, 16, 512L, Wrhi, Wrlo, 512L, C2, 1024L, 16, 8, 1, 16);

  epilogue_kernel<<<dim3(2048), 256, 0, stream>>>(C1, C2, out);
}